// Round 1
// baseline (842.840 us; speedup 1.0000x reference)
//
#include <hip/hip_runtime.h>

#define N_SEGMENTS 50000
#define N_ROWS     1600000
#define N_FEAT     64

// ---------------- Fallback (previous verified kernel) ----------------
__global__ void seg_sum_atomic(const float* __restrict__ in,
                               const int*   __restrict__ idx,
                               float*       __restrict__ out) {
    long long t   = (long long)blockIdx.x * blockDim.x + threadIdx.x;
    long long row = t >> 6;
    int       c   = (int)(t & 63);
    if (row < (long long)N_ROWS) {
        int s = idx[row];
        float v = in[row * N_FEAT + c];
        atomicAdd(out + (long long)s * N_FEAT + c, v);
    }
}

// ---------------- Phase 1: per-segment row counts ----------------
// int4 loads: 4 rows/thread. Counters (200 KB) stay hot in L2/L3,
// so these int atomics are cheap compared to 102M float atomics.
__global__ void hist_kernel(const int* __restrict__ idx, int* __restrict__ cnt) {
    int t = blockIdx.x * blockDim.x + threadIdx.x;
    int r = t << 2;
    if (r < N_ROWS) {
        int4 v = *reinterpret_cast<const int4*>(idx + r);
        atomicAdd(&cnt[v.x], 1);
        atomicAdd(&cnt[v.y], 1);
        atomicAdd(&cnt[v.z], 1);
        atomicAdd(&cnt[v.w], 1);
    }
}

// ---------------- Phase 2: exclusive scan, single block ----------------
// 50000 elements: each of 1024 threads serially sums a 49-wide chunk,
// Hillis-Steele scan over the 1024 partials in LDS, then re-walk chunk.
__global__ void __launch_bounds__(1024) scan_kernel(const int* __restrict__ cnt,
                                                    int* __restrict__ base,
                                                    int* __restrict__ cursor) {
    __shared__ int part[1024];
    int t = threadIdx.x;
    const int CHUNK = (N_SEGMENTS + 1023) / 1024;   // 49
    int lo = t * CHUNK;
    int hi = lo + CHUNK; if (hi > N_SEGMENTS) hi = N_SEGMENTS;
    if (lo > N_SEGMENTS) lo = N_SEGMENTS;
    int sum = 0;
    for (int i = lo; i < hi; ++i) sum += cnt[i];
    part[t] = sum;
    __syncthreads();
    for (int ofs = 1; ofs < 1024; ofs <<= 1) {
        int v = (t >= ofs) ? part[t - ofs] : 0;
        __syncthreads();
        part[t] += v;
        __syncthreads();
    }
    int run = (t == 0) ? 0 : part[t - 1];
    for (int i = lo; i < hi; ++i) {
        base[i]   = run;
        cursor[i] = run;
        run += cnt[i];
    }
    if (t == 1023) base[N_SEGMENTS] = N_ROWS;
}

// ---------------- Phase 3: scatter row ids into segment bins ----------------
__global__ void scatter_kernel(const int* __restrict__ idx,
                               int* __restrict__ cursor,
                               int* __restrict__ rowids) {
    int t = blockIdx.x * blockDim.x + threadIdx.x;
    int r = t << 2;
    if (r < N_ROWS) {
        int4 v = *reinterpret_cast<const int4*>(idx + r);
        rowids[atomicAdd(&cursor[v.x], 1)] = r;
        rowids[atomicAdd(&cursor[v.y], 1)] = r + 1;
        rowids[atomicAdd(&cursor[v.z], 1)] = r + 2;
        rowids[atomicAdd(&cursor[v.w], 1)] = r + 3;
    }
}

// ---------------- Phase 4: one wave per segment, gather + sum ----------------
// Lane-parallel row-id prefetch (up to 64 ids at once), redistributed with
// __shfl (ds_bpermute, cheap). 4 independent accumulators keep 4 row loads
// in flight. Each row read is 256B contiguous -> 4 fully-used cache lines.
// Plain coalesced store; empty segments write 0 (so no output memset needed).
__global__ void gather_kernel(const float* __restrict__ in,
                              const int*   __restrict__ rowids,
                              const int*   __restrict__ base,
                              float*       __restrict__ out) {
    int wave = (blockIdx.x * blockDim.x + threadIdx.x) >> 6;
    int lane = threadIdx.x & 63;
    if (wave >= N_SEGMENTS) return;
    int beg = base[wave];
    int end = base[wave + 1];
    float a0 = 0.f, a1 = 0.f, a2 = 0.f, a3 = 0.f;
    for (int j0 = beg; j0 < end; j0 += 64) {
        int n = end - j0; if (n > 64) n = 64;
        int myid = (lane < n) ? rowids[j0 + lane] : 0;
        int k = 0;
        for (; k + 4 <= n; k += 4) {
            int r0 = __shfl(myid, k);
            int r1 = __shfl(myid, k + 1);
            int r2 = __shfl(myid, k + 2);
            int r3 = __shfl(myid, k + 3);
            a0 += in[r0 * N_FEAT + lane];   // row*64+lane < 2^31, int ok
            a1 += in[r1 * N_FEAT + lane];
            a2 += in[r2 * N_FEAT + lane];
            a3 += in[r3 * N_FEAT + lane];
        }
        for (; k < n; ++k) {
            int r = __shfl(myid, k);
            a0 += in[r * N_FEAT + lane];
        }
    }
    out[wave * N_FEAT + lane] = (a0 + a1) + (a2 + a3);
}

extern "C" void kernel_launch(void* const* d_in, const int* in_sizes, int n_in,
                              void* d_out, int out_size, void* d_ws, size_t ws_size,
                              hipStream_t stream) {
    const float* in  = (const float*)d_in[0];
    const int*   idx = (const int*)d_in[1];
    float*       out = (float*)d_out;

    // Workspace layout: cnt[50000] | base[50001] | cursor[50000] | rowids[1.6M]
    const size_t need = ((size_t)N_SEGMENTS * 3 + 1 + N_ROWS) * sizeof(int);
    if (ws_size < need) {
        // Fallback: previous verified atomic kernel.
        hipMemsetAsync(d_out, 0, (size_t)out_size * sizeof(float), stream);
        const long long total = (long long)N_ROWS * N_FEAT;
        const int block = 256;
        const long long grid = (total + block - 1) / block;
        seg_sum_atomic<<<(unsigned)grid, block, 0, stream>>>(in, idx, out);
        return;
    }

    int* cnt    = (int*)d_ws;
    int* base   = cnt + N_SEGMENTS;
    int* cursor = base + N_SEGMENTS + 1;
    int* rowids = cursor + N_SEGMENTS;

    hipMemsetAsync(cnt, 0, (size_t)N_SEGMENTS * sizeof(int), stream);

    const int block = 256;
    const int gridRows = (N_ROWS / 4 + block - 1) / block;   // 4 rows/thread
    hist_kernel   <<<gridRows, block, 0, stream>>>(idx, cnt);
    scan_kernel   <<<1, 1024, 0, stream>>>(cnt, base, cursor);
    scatter_kernel<<<gridRows, block, 0, stream>>>(idx, cursor, rowids);

    const int gridGather = (N_SEGMENTS * 64) / 256;          // 12500 blocks
    gather_kernel <<<gridGather, block, 0, stream>>>(in, rowids, base, out);
}

// Round 2
// 838.618 us; speedup vs baseline: 1.0050x; 1.0050x over previous
//
#include <hip/hip_runtime.h>

#define N_SEGMENTS 50000
#define N_ROWS     1600000
#define N_FEAT     64

// ---------------- Fallback (round-0 verified kernel) ----------------
__global__ void seg_sum_atomic(const float* __restrict__ in,
                               const int*   __restrict__ idx,
                               float*       __restrict__ out) {
    long long t   = (long long)blockIdx.x * blockDim.x + threadIdx.x;
    long long row = t >> 6;
    int       c   = (int)(t & 63);
    if (row < (long long)N_ROWS) {
        int s = idx[row];
        float v = in[row * N_FEAT + c];
        atomicAdd(out + (long long)s * N_FEAT + c, v);
    }
}

// ---------------- Phase 1: per-segment row counts ----------------
__global__ void hist_kernel(const int* __restrict__ idx, int* __restrict__ cnt) {
    int t = blockIdx.x * blockDim.x + threadIdx.x;
    int r = t << 2;
    if (r < N_ROWS) {
        int4 v = *reinterpret_cast<const int4*>(idx + r);
        atomicAdd(&cnt[v.x], 1);
        atomicAdd(&cnt[v.y], 1);
        atomicAdd(&cnt[v.z], 1);
        atomicAdd(&cnt[v.w], 1);
    }
}

// ---------------- Phase 2: exclusive scan, single block ----------------
__global__ void __launch_bounds__(1024) scan_kernel(const int* __restrict__ cnt,
                                                    int* __restrict__ base,
                                                    int* __restrict__ cursor) {
    __shared__ int part[1024];
    int t = threadIdx.x;
    const int CHUNK = (N_SEGMENTS + 1023) / 1024;   // 49
    int lo = t * CHUNK;
    int hi = lo + CHUNK; if (hi > N_SEGMENTS) hi = N_SEGMENTS;
    if (lo > N_SEGMENTS) lo = N_SEGMENTS;
    int sum = 0;
    for (int i = lo; i < hi; ++i) sum += cnt[i];
    part[t] = sum;
    __syncthreads();
    for (int ofs = 1; ofs < 1024; ofs <<= 1) {
        int v = (t >= ofs) ? part[t - ofs] : 0;
        __syncthreads();
        part[t] += v;
        __syncthreads();
    }
    int run = (t == 0) ? 0 : part[t - 1];
    for (int i = lo; i < hi; ++i) {
        base[i]   = run;
        cursor[i] = run;
        run += cnt[i];
    }
    if (t == 1023) base[N_SEGMENTS] = N_ROWS;
}

// ---------------- Phase 3: scatter row ids into segment bins ----------------
__global__ void scatter_kernel(const int* __restrict__ idx,
                               int* __restrict__ cursor,
                               int* __restrict__ rowids) {
    int t = blockIdx.x * blockDim.x + threadIdx.x;
    int r = t << 2;
    if (r < N_ROWS) {
        int4 v = *reinterpret_cast<const int4*>(idx + r);
        rowids[atomicAdd(&cursor[v.x], 1)] = r;
        rowids[atomicAdd(&cursor[v.y], 1)] = r + 1;
        rowids[atomicAdd(&cursor[v.z], 1)] = r + 2;
        rowids[atomicAdd(&cursor[v.w], 1)] = r + 3;
    }
}

// ---------------- Phase 4: one wave per segment, float4 gather ----------------
// Lane L: q = L>>4 selects one of 4 row-slots, f = L&15 selects a 16B feature
// block. One global_load_dwordx4 per lane covers 4 FULL rows per wave-instr
// (1 KB/instr). 4 accumulators -> 16 rows in flight. Final shfl_xor(16,32)
// folds the 4 row-slots; lanes 0..15 store the 256B output row as float4.
// Empty segments store zeros, so no output memset is needed.
__device__ __forceinline__ float4 fadd4(float4 a, float4 b) {
    a.x += b.x; a.y += b.y; a.z += b.z; a.w += b.w; return a;
}

__global__ void gather_kernel(const float* __restrict__ in,
                              const int*   __restrict__ rowids,
                              const int*   __restrict__ base,
                              float*       __restrict__ out) {
    int wave = (blockIdx.x * blockDim.x + threadIdx.x) >> 6;
    int lane = threadIdx.x & 63;
    if (wave >= N_SEGMENTS) return;
    int q = lane >> 4;      // row-slot 0..3
    int f = lane & 15;      // feature block (4 floats)
    int beg = base[wave];
    int end = base[wave + 1];
    float4 z = {0.f, 0.f, 0.f, 0.f};
    float4 a0 = z, a1 = z, a2 = z, a3 = z;

    for (int j0 = beg; j0 < end; j0 += 64) {
        int n = end - j0; if (n > 64) n = 64;
        int myid = (lane < n) ? rowids[j0 + lane] : 0;
        for (int k = 0; k < n; k += 16) {
            int i0 = k + q, i1 = k + 4 + q, i2 = k + 8 + q, i3 = k + 12 + q;
            int r0 = __shfl(myid, i0 < n ? i0 : 0);
            int r1 = __shfl(myid, i1 < n ? i1 : 0);
            int r2 = __shfl(myid, i2 < n ? i2 : 0);
            int r3 = __shfl(myid, i3 < n ? i3 : 0);
            float4 v0 = *reinterpret_cast<const float4*>(in + (long long)r0 * N_FEAT + f * 4);
            float4 v1 = *reinterpret_cast<const float4*>(in + (long long)r1 * N_FEAT + f * 4);
            float4 v2 = *reinterpret_cast<const float4*>(in + (long long)r2 * N_FEAT + f * 4);
            float4 v3 = *reinterpret_cast<const float4*>(in + (long long)r3 * N_FEAT + f * 4);
            if (i0 < n) a0 = fadd4(a0, v0);
            if (i1 < n) a1 = fadd4(a1, v1);
            if (i2 < n) a2 = fadd4(a2, v2);
            if (i3 < n) a3 = fadd4(a3, v3);
        }
    }

    float4 a = fadd4(fadd4(a0, a1), fadd4(a2, a3));
    // fold the 4 row-slot groups (lanes L, L^16, L^32, L^48)
    a.x += __shfl_xor(a.x, 16); a.y += __shfl_xor(a.y, 16);
    a.z += __shfl_xor(a.z, 16); a.w += __shfl_xor(a.w, 16);
    a.x += __shfl_xor(a.x, 32); a.y += __shfl_xor(a.y, 32);
    a.z += __shfl_xor(a.z, 32); a.w += __shfl_xor(a.w, 32);

    if (q == 0) {
        *reinterpret_cast<float4*>(out + (size_t)wave * N_FEAT + f * 4) = a;
    }
}

extern "C" void kernel_launch(void* const* d_in, const int* in_sizes, int n_in,
                              void* d_out, int out_size, void* d_ws, size_t ws_size,
                              hipStream_t stream) {
    const float* in  = (const float*)d_in[0];
    const int*   idx = (const int*)d_in[1];
    float*       out = (float*)d_out;

    // Workspace layout: cnt[50000] | base[50001] | cursor[50000] | rowids[1.6M]
    const size_t need = ((size_t)N_SEGMENTS * 3 + 1 + N_ROWS) * sizeof(int);
    if (ws_size < need) {
        hipMemsetAsync(d_out, 0, (size_t)out_size * sizeof(float), stream);
        const long long total = (long long)N_ROWS * N_FEAT;
        const int block = 256;
        const long long grid = (total + block - 1) / block;
        seg_sum_atomic<<<(unsigned)grid, block, 0, stream>>>(in, idx, out);
        return;
    }

    int* cnt    = (int*)d_ws;
    int* base   = cnt + N_SEGMENTS;
    int* cursor = base + N_SEGMENTS + 1;
    int* rowids = cursor + N_SEGMENTS;

    hipMemsetAsync(cnt, 0, (size_t)N_SEGMENTS * sizeof(int), stream);

    const int block = 256;
    const int gridRows = (N_ROWS / 4 + block - 1) / block;   // 1563 blocks
    hist_kernel   <<<gridRows, block, 0, stream>>>(idx, cnt);
    scan_kernel   <<<1, 1024, 0, stream>>>(cnt, base, cursor);
    scatter_kernel<<<gridRows, block, 0, stream>>>(idx, cursor, rowids);

    const int gridGather = (N_SEGMENTS * 64) / 256;          // 12500 blocks
    gather_kernel <<<gridGather, block, 0, stream>>>(in, rowids, base, out);
}

// Round 4
// 705.480 us; speedup vs baseline: 1.1947x; 1.1887x over previous
//
#include <hip/hip_runtime.h>

#define N_SEGMENTS 50000
#define N_ROWS     1600000
#define N_FEAT     64
#define SCHUNK     1000     // scan chunk per block
#define N_CHUNKS   50       // N_SEGMENTS / SCHUNK

// Native vector type: __builtin_nontemporal_load/store require scalar/native-
// vector element pointers (HIP_vector_type<float,4> is rejected).
typedef float f32x4 __attribute__((ext_vector_type(4)));

// ---------------- Fallback (round-0 verified kernel) ----------------
__global__ void seg_sum_atomic(const float* __restrict__ in,
                               const int*   __restrict__ idx,
                               float*       __restrict__ out) {
    long long t   = (long long)blockIdx.x * blockDim.x + threadIdx.x;
    long long row = t >> 6;
    int       c   = (int)(t & 63);
    if (row < (long long)N_ROWS) {
        int s = idx[row];
        float v = in[row * N_FEAT + c];
        atomicAdd(out + (long long)s * N_FEAT + c, v);
    }
}

// ---------------- Phase 1: per-segment row counts ----------------
__global__ void hist_kernel(const int* __restrict__ idx, int* __restrict__ cnt) {
    int t = blockIdx.x * blockDim.x + threadIdx.x;
    int r = t << 2;
    if (r < N_ROWS) {
        int4 v = *reinterpret_cast<const int4*>(idx + r);
        atomicAdd(&cnt[v.x], 1);
        atomicAdd(&cnt[v.y], 1);
        atomicAdd(&cnt[v.z], 1);
        atomicAdd(&cnt[v.w], 1);
    }
}

// ---------------- Phase 2a: per-chunk local exclusive scan (50 blocks) -------
__global__ void __launch_bounds__(1024) scan_part(const int* __restrict__ cnt,
                                                  int* __restrict__ base,
                                                  int* __restrict__ cursor,
                                                  int* __restrict__ csum) {
    __shared__ int part[1024];
    int b = blockIdx.x;
    int t = threadIdx.x;
    int g = b * SCHUNK + t;
    part[t] = (t < SCHUNK) ? cnt[g] : 0;
    __syncthreads();
    for (int ofs = 1; ofs < 1024; ofs <<= 1) {
        int u = (t >= ofs) ? part[t - ofs] : 0;
        __syncthreads();
        part[t] += u;
        __syncthreads();
    }
    int excl = (t == 0) ? 0 : part[t - 1];
    if (t < SCHUNK) { base[g] = excl; cursor[g] = excl; }
    if (t == 1023) csum[b] = part[1023];   // chunk total (padding is zero)
}

// ---------------- Phase 2b: scan the 50 chunk totals (1 wave) ----------------
// off[c] = exclusive prefix of chunk totals; off[N_CHUNKS] = N_ROWS.
// global_prefix(i) = base[i] + off[i/1000]; base[N_SEGMENTS] = 0.
__global__ void scan_fix(const int* __restrict__ csum,
                         int* __restrict__ off,
                         int* __restrict__ base) {
    int t = threadIdx.x;                     // 64 threads
    int orig = (t < N_CHUNKS) ? csum[t] : 0;
    int v = orig;
    for (int ofs = 1; ofs < 64; ofs <<= 1) {
        int u = __shfl_up(v, ofs);
        if (t >= ofs) v += u;
    }
    if (t < N_CHUNKS) off[t] = v - orig;     // exclusive
    if (t == N_CHUNKS - 1) { off[N_CHUNKS] = v; base[N_SEGMENTS] = 0; }
}

// ---------------- Phase 3: scatter row ids into segment bins ----------------
__global__ void scatter_kernel(const int* __restrict__ idx,
                               int* __restrict__ cursor,
                               const int* __restrict__ off,
                               int* __restrict__ rowids) {
    int t = blockIdx.x * blockDim.x + threadIdx.x;
    int r = t << 2;
    if (r < N_ROWS) {
        int4 v = *reinterpret_cast<const int4*>(idx + r);
        rowids[atomicAdd(&cursor[v.x], 1) + off[v.x / SCHUNK]] = r;
        rowids[atomicAdd(&cursor[v.y], 1) + off[v.y / SCHUNK]] = r + 1;
        rowids[atomicAdd(&cursor[v.z], 1) + off[v.z / SCHUNK]] = r + 2;
        rowids[atomicAdd(&cursor[v.w], 1) + off[v.w / SCHUNK]] = r + 3;
    }
}

// ---------------- Phase 4: one wave per segment, float4 gather ----------------
// Lane L: q = L>>4 (row-slot), f = L&15 (16B feature block). Static 4x-unrolled
// inner loop: all 16 global_load_dwordx4 issue before any accumulate waits
// (max MLP). OOB slots clamp to slot 0 -> L1-hit duplicate loads, guarded adds.
// Nontemporal row loads keep the 409.6MB single-use stream out of L2.
__device__ __forceinline__ f32x4 fadd4(f32x4 a, f32x4 b) { return a + b; }

__global__ void gather_kernel(const float* __restrict__ in,
                              const int*   __restrict__ rowids,
                              const int*   __restrict__ base,
                              const int*   __restrict__ off,
                              float*       __restrict__ out) {
    int wave = (blockIdx.x * blockDim.x + threadIdx.x) >> 6;
    int lane = threadIdx.x & 63;
    if (wave >= N_SEGMENTS) return;
    int q = lane >> 4;
    int f = lane & 15;
    int beg = base[wave]     + off[wave / SCHUNK];
    int end = base[wave + 1] + off[(wave + 1) / SCHUNK];
    f32x4 z = {0.f, 0.f, 0.f, 0.f};
    f32x4 a0 = z, a1 = z, a2 = z, a3 = z;

    for (int j0 = beg; j0 < end; j0 += 64) {
        int n = end - j0; if (n > 64) n = 64;
        int myid = (lane < n) ? rowids[j0 + lane] : 0;
#pragma unroll
        for (int k = 0; k < 64; k += 16) {
            int i0 = k + q, i1 = k + 4 + q, i2 = k + 8 + q, i3 = k + 12 + q;
            int r0 = __shfl(myid, i0 < n ? i0 : 0);
            int r1 = __shfl(myid, i1 < n ? i1 : 0);
            int r2 = __shfl(myid, i2 < n ? i2 : 0);
            int r3 = __shfl(myid, i3 < n ? i3 : 0);
            f32x4 v0 = __builtin_nontemporal_load(
                reinterpret_cast<const f32x4*>(in + (long long)r0 * N_FEAT + f * 4));
            f32x4 v1 = __builtin_nontemporal_load(
                reinterpret_cast<const f32x4*>(in + (long long)r1 * N_FEAT + f * 4));
            f32x4 v2 = __builtin_nontemporal_load(
                reinterpret_cast<const f32x4*>(in + (long long)r2 * N_FEAT + f * 4));
            f32x4 v3 = __builtin_nontemporal_load(
                reinterpret_cast<const f32x4*>(in + (long long)r3 * N_FEAT + f * 4));
            if (i0 < n) a0 = fadd4(a0, v0);
            if (i1 < n) a1 = fadd4(a1, v1);
            if (i2 < n) a2 = fadd4(a2, v2);
            if (i3 < n) a3 = fadd4(a3, v3);
        }
    }

    f32x4 a = fadd4(fadd4(a0, a1), fadd4(a2, a3));
    a.x += __shfl_xor(a.x, 16); a.y += __shfl_xor(a.y, 16);
    a.z += __shfl_xor(a.z, 16); a.w += __shfl_xor(a.w, 16);
    a.x += __shfl_xor(a.x, 32); a.y += __shfl_xor(a.y, 32);
    a.z += __shfl_xor(a.z, 32); a.w += __shfl_xor(a.w, 32);

    if (q == 0) {
        __builtin_nontemporal_store(a,
            reinterpret_cast<f32x4*>(out + (size_t)wave * N_FEAT + f * 4));
    }
}

extern "C" void kernel_launch(void* const* d_in, const int* in_sizes, int n_in,
                              void* d_out, int out_size, void* d_ws, size_t ws_size,
                              hipStream_t stream) {
    const float* in  = (const float*)d_in[0];
    const int*   idx = (const int*)d_in[1];
    float*       out = (float*)d_out;

    // ws ints: cnt[50000] | base[50001] | cursor[50000] | csum[64] | off[64] | rowids[1.6M]
    const size_t need = ((size_t)N_SEGMENTS * 3 + 1 + 128 + N_ROWS) * sizeof(int);
    if (ws_size < need) {
        (void)hipMemsetAsync(d_out, 0, (size_t)out_size * sizeof(float), stream);
        const long long total = (long long)N_ROWS * N_FEAT;
        const int block = 256;
        const long long grid = (total + block - 1) / block;
        seg_sum_atomic<<<(unsigned)grid, block, 0, stream>>>(in, idx, out);
        return;
    }

    int* cnt    = (int*)d_ws;
    int* base   = cnt + N_SEGMENTS;          // [N_SEGMENTS+1]
    int* cursor = base + N_SEGMENTS + 1;
    int* csum   = cursor + N_SEGMENTS;       // [64]
    int* off    = csum + 64;                 // [64] (uses N_CHUNKS+1)
    int* rowids = off + 64;

    (void)hipMemsetAsync(cnt, 0, (size_t)N_SEGMENTS * sizeof(int), stream);

    const int block = 256;
    const int gridRows = (N_ROWS / 4 + block - 1) / block;   // 1563 blocks
    hist_kernel   <<<gridRows, block, 0, stream>>>(idx, cnt);
    scan_part     <<<N_CHUNKS, 1024, 0, stream>>>(cnt, base, cursor, csum);
    scan_fix      <<<1, 64, 0, stream>>>(csum, off, base);
    scatter_kernel<<<gridRows, block, 0, stream>>>(idx, cursor, off, rowids);

    const int gridGather = (N_SEGMENTS * 64) / 256;          // 12500 blocks
    gather_kernel <<<gridGather, block, 0, stream>>>(in, rowids, base, off, out);
}